// Round 3
// baseline (477.925 us; speedup 1.0000x reference)
//
#include <hip/hip_runtime.h>
#include <hip/hip_cooperative_groups.h>
#include <math.h>

namespace cg = cooperative_groups;

#define F_OUT 128
#define N_HEAD 4
#define CB 768    // cooperative grid blocks (3 per CU, <= co-residency limit)
#define CT 256    // threads per block (4 waves)
#define EPT 4     // edges per thread: 768*256*4 = 786432 >= 600000

// ---------------- workspace layout (byte offsets, 16B-aligned) ---------------
#define WS_SRCDOT  0         // N*4 f32      (800000 B)
#define WS_RELDOT  800000    // NREL*4 f32   (8000 B)
#define WS_COUNTS  808000    // N int        (200000 B)
#define WS_OFFSETS 1008000   // (N+1) int    (200016 B)
#define WS_SPK     1208016   // E u32        (2400000 B)   packed (rel<<16)|src

// ============================================================================
// Cooperative kernel: hist (+rank in regs) | srcdot | reldot  -> grid.sync ->
// block-0 scan counts->offsets -> grid.sync -> scatter packed (rel,src).
// ============================================================================
__global__ void __launch_bounds__(CT, 4)
coop_kernel(const float* __restrict__ h, const float* __restrict__ inputr,
            const float* __restrict__ w, const float* __restrict__ a,
            const int* __restrict__ A,
            float* __restrict__ srcdot, float* __restrict__ reldot,
            int* __restrict__ counts, int* __restrict__ offsets,
            unsigned* __restrict__ sPK, int N, int NREL, int E) {
    cg::grid_group grid = cg::this_grid();
    const int t = threadIdx.x;
    const int b = blockIdx.x;

    // ---- Phase A1: histogram of dst; keep (dst,rel,src,rank) in registers.
    int e_dst[EPT], e_rel[EPT], e_src[EPT], e_rank[EPT];
    #pragma unroll
    for (int k = 0; k < EPT; ++k) {
        int e = (b * EPT + k) * CT + t;   // coalesced per k
        e_dst[k] = -1;
        if (e < E) {
            int d = A[e];
            e_dst[k]  = d;
            e_rel[k]  = A[E + e];
            e_src[k]  = A[2 * E + e];
            e_rank[k] = atomicAdd(&counts[d], 1);   // rank within dst bucket
        }
    }

    // ---- Phase A2: srcdot[n][i] = h0[n] . (cumw_i * a_src_i), wave per node.
    const int lane = t & 63;
    const int wave = (b * CT + t) >> 6;
    const int nwaves = CB * (CT / 64);
    float b0[N_HEAD], b1[N_HEAD];
    {
        float cwa[N_HEAD], cwb[N_HEAD];
        cwa[0] = 1.0f;
        cwa[1] = w[lane];
        cwa[2] = cwa[1] * w[F_OUT + lane];
        cwa[3] = cwa[2] * w[2 * F_OUT + lane];
        cwb[0] = 1.0f;
        cwb[1] = w[64 + lane];
        cwb[2] = cwb[1] * w[F_OUT + 64 + lane];
        cwb[3] = cwb[2] * w[2 * F_OUT + 64 + lane];
        #pragma unroll
        for (int i = 0; i < N_HEAD; ++i) {
            b0[i] = cwa[i] * a[(i * 2) * F_OUT + lane];
            b1[i] = cwb[i] * a[(i * 2) * F_OUT + 64 + lane];
        }
    }
    for (int n = wave; n < N; n += nwaves) {
        float x0 = h[n * F_OUT + lane];
        float x1 = h[n * F_OUT + 64 + lane];
        float p[N_HEAD];
        #pragma unroll
        for (int i = 0; i < N_HEAD; ++i) p[i] = x0 * b0[i] + x1 * b1[i];
        #pragma unroll
        for (int off = 32; off > 0; off >>= 1) {
            #pragma unroll
            for (int i = 0; i < N_HEAD; ++i) p[i] += __shfl_down(p[i], off);
        }
        if (lane == 0)
            *(float4*)(srcdot + n * 4) = make_float4(p[0], p[1], p[2], p[3]);
    }

    // ---- Phase A3: reldot[r][i] = inputr[r] . a_dst_i, wave per rel.
    {
        float d0[N_HEAD], d1[N_HEAD];
        #pragma unroll
        for (int i = 0; i < N_HEAD; ++i) {
            d0[i] = a[(i * 2 + 1) * F_OUT + lane];
            d1[i] = a[(i * 2 + 1) * F_OUT + 64 + lane];
        }
        for (int r = wave; r < NREL; r += nwaves) {
            float x0 = inputr[r * F_OUT + lane];
            float x1 = inputr[r * F_OUT + 64 + lane];
            float p[N_HEAD];
            #pragma unroll
            for (int i = 0; i < N_HEAD; ++i) p[i] = x0 * d0[i] + x1 * d1[i];
            #pragma unroll
            for (int off = 32; off > 0; off >>= 1) {
                #pragma unroll
                for (int i = 0; i < N_HEAD; ++i) p[i] += __shfl_down(p[i], off);
            }
            if (lane == 0)
                *(float4*)(reldot + r * 4) = make_float4(p[0], p[1], p[2], p[3]);
        }
    }

    grid.sync();

    // ---- Phase B: block 0 scans counts -> offsets (exclusive).
    __shared__ int tsum[CT];
    if (b == 0) {
        const int CH = (N + CT - 1) / CT;   // 196
        int base = t * CH;
        int s = 0;
        for (int j = 0; j < CH; ++j) {
            int idx = base + j;
            if (idx < N) s += counts[idx];
        }
        tsum[t] = s;
        __syncthreads();
        for (int off = 1; off < CT; off <<= 1) {
            int u = (t >= off) ? tsum[t - off] : 0;
            __syncthreads();
            tsum[t] += u;
            __syncthreads();
        }
        int run = (t == 0) ? 0 : tsum[t - 1];
        for (int j = 0; j < CH; ++j) {
            int idx = base + j;
            if (idx < N) { offsets[idx] = run; run += counts[idx]; }
        }
        if (t == 0) offsets[N] = E;
    }

    grid.sync();

    // ---- Phase C: scatter packed (rel,src) straight from registers.
    #pragma unroll
    for (int k = 0; k < EPT; ++k) {
        if (e_dst[k] >= 0) {
            int idx = offsets[e_dst[k]] + e_rank[k];
            sPK[idx] = ((unsigned)e_rel[k] << 16) | (unsigned)e_src[k];
        }
    }
}

// ============================================================================
// Per-node accumulation. grid=N, block=128 (thread = column). ee computed on
// the fly from srcdot/reldot during LDS staging (logit has no dst dependence).
// ============================================================================
#define STAGE 128
__global__ void __launch_bounds__(128)
node_kernel(const float* __restrict__ h, const float* __restrict__ inputr,
            const float* __restrict__ w,
            const float* __restrict__ srcdot, const float* __restrict__ reldot,
            const int* __restrict__ offsets, const unsigned* __restrict__ sPK,
            float* __restrict__ out, int N) {
    __shared__ float4 see[STAGE];
    __shared__ unsigned spk[STAGE];
    int n = blockIdx.x;
    int c = threadIdx.x;
    int s0 = offsets[n];
    int s1 = offsets[n + 1];
    float a1[N_HEAD] = {0, 0, 0, 0};
    float a2[N_HEAD] = {0, 0, 0, 0};
    float rs[N_HEAD] = {0, 0, 0, 0};
    for (int base = s0; base < s1; base += STAGE) {
        int cnt = min(STAGE, s1 - base);
        if (c < cnt) {
            unsigned pk = sPK[base + c];
            spk[c] = pk;
            float4 sd = *(const float4*)(srcdot + (pk & 0xFFFFu) * 4);
            float4 rd = *(const float4*)(reldot + (pk >> 16) * 4);
            float4 ee;
            float l;
            l = sd.x + rd.x; ee.x = __expf(-(l > 0.0f ? l : 0.2f * l));
            l = sd.y + rd.y; ee.y = __expf(-(l > 0.0f ? l : 0.2f * l));
            l = sd.z + rd.z; ee.z = __expf(-(l > 0.0f ? l : 0.2f * l));
            l = sd.w + rd.w; ee.w = __expf(-(l > 0.0f ? l : 0.2f * l));
            see[c] = ee;
        }
        __syncthreads();
        #pragma unroll 4
        for (int j = 0; j < cnt; ++j) {
            float4 ee = see[j];
            unsigned pk = spk[j];
            float hc = h[(pk & 0xFFFFu) * F_OUT + c];
            float rc = inputr[(pk >> 16) * F_OUT + c];
            a1[0] += hc * ee.x;  a2[0] += rc * ee.x;  rs[0] += ee.x;
            a1[1] += hc * ee.y;  a2[1] += rc * ee.y;  rs[1] += ee.y;
            a1[2] += hc * ee.z;  a2[2] += rc * ee.z;  rs[2] += ee.z;
            a1[3] += hc * ee.w;  a2[3] += rc * ee.w;  rs[3] += ee.w;
        }
        __syncthreads();
    }
    float cw1 = w[c];
    float cw2 = cw1 * w[F_OUT + c];
    float cw3 = cw2 * w[2 * F_OUT + c];
    float cwv[N_HEAD] = {1.0f, cw1, cw2, cw3};
    #pragma unroll
    for (int i = 0; i < N_HEAD; ++i) {
        out[((size_t)i * N + n) * F_OUT + c] = (cwv[i] * a1[i] - a2[i]) / rs[i];
    }
}

extern "C" void kernel_launch(void* const* d_in, const int* in_sizes, int n_in,
                              void* d_out, int out_size, void* d_ws, size_t ws_size,
                              hipStream_t stream) {
    const float* h      = (const float*)d_in[0];
    const float* inputr = (const float*)d_in[1];
    const float* w      = (const float*)d_in[2];
    const float* a      = (const float*)d_in[3];
    const int*   A      = (const int*)d_in[4];
    float* out = (float*)d_out;

    int N    = in_sizes[0] / F_OUT;   // 50000
    int NREL = in_sizes[1] / F_OUT;   // 500
    int E    = in_sizes[4] / 3;       // 600000

    char* ws = (char*)d_ws;
    float*    srcdot  = (float*)(ws + WS_SRCDOT);
    float*    reldot  = (float*)(ws + WS_RELDOT);
    int*      counts  = (int*)(ws + WS_COUNTS);
    int*      offsets = (int*)(ws + WS_OFFSETS);
    unsigned* sPK     = (unsigned*)(ws + WS_SPK);

    hipMemsetAsync(counts, 0, (size_t)N * sizeof(int), stream);

    void* args[] = {
        (void*)&h, (void*)&inputr, (void*)&w, (void*)&a, (void*)&A,
        (void*)&srcdot, (void*)&reldot, (void*)&counts, (void*)&offsets,
        (void*)&sPK, (void*)&N, (void*)&NREL, (void*)&E
    };
    hipLaunchCooperativeKernel((void*)coop_kernel, dim3(CB), dim3(CT),
                               args, 0, stream);

    node_kernel<<<N, 128, 0, stream>>>(h, inputr, w, srcdot, reldot,
                                       offsets, sPK, out, N);
}

// Round 4
// 251.326 us; speedup vs baseline: 1.9016x; 1.9016x over previous
//
#include <hip/hip_runtime.h>
#include <math.h>

#define F_OUT 128
#define N_HEAD 4
#define SCAN_CHUNK 2048

// ---------------- workspace layout (byte offsets, 16B-aligned) ---------------
#define WS_SRCDOT  0         // N*4 f32      (800000 B)
#define WS_RELDOT  800000    // NREL*4 f32   (8000 B)
#define WS_COUNTS  808000    // N int        (200000 B)
#define WS_OFFSETS 1008000   // (N+1) int    (200016 B)
#define WS_CURSOR  1208016   // N int        (200000 B)
#define WS_BSUM    1408016   // 128 int      (512 B)
#define WS_SPK     1408528   // E u32        (2400000 B)  packed (rel<<16)|src

// ============================================================================
// Fused preprocessing: [0,SB) srcdot | [SB,SB+RB) reldot | rest: dst histogram.
// All three are independent — no sync needed, just disjoint block ranges.
// ============================================================================
__global__ __launch_bounds__(256)
void fused_pre(const float* __restrict__ h, const float* __restrict__ inputr,
               const float* __restrict__ w, const float* __restrict__ a,
               const int* __restrict__ A,
               float* __restrict__ srcdot, float* __restrict__ reldot,
               int* __restrict__ counts,
               int N, int NREL, int E, int SB, int RB) {
    int blk = blockIdx.x;
    int t = threadIdx.x;
    int lane = t & 63;

    if (blk < SB) {
        // ---- srcdot[n][i] = h0[n] . (cumw_i * a_src_i), wave per node
        int n = blk * 4 + (t >> 6);
        if (n >= N) return;
        float c1a = w[lane],            c1b = w[64 + lane];
        float c2a = c1a * w[F_OUT + lane], c2b = c1b * w[F_OUT + 64 + lane];
        float c3a = c2a * w[2 * F_OUT + lane], c3b = c2b * w[2 * F_OUT + 64 + lane];
        float cwa[N_HEAD] = {1.0f, c1a, c2a, c3a};
        float cwb[N_HEAD] = {1.0f, c1b, c2b, c3b};
        float x0 = h[n * F_OUT + lane];
        float x1 = h[n * F_OUT + 64 + lane];
        float p[N_HEAD];
        #pragma unroll
        for (int i = 0; i < N_HEAD; ++i)
            p[i] = x0 * (cwa[i] * a[(i * 2) * F_OUT + lane])
                 + x1 * (cwb[i] * a[(i * 2) * F_OUT + 64 + lane]);
        #pragma unroll
        for (int off = 32; off > 0; off >>= 1) {
            #pragma unroll
            for (int i = 0; i < N_HEAD; ++i) p[i] += __shfl_down(p[i], off);
        }
        if (lane == 0)
            *(float4*)(srcdot + n * 4) = make_float4(p[0], p[1], p[2], p[3]);
    } else if (blk < SB + RB) {
        // ---- reldot[r][i] = inputr[r] . a_dst_i, wave per rel
        int r = (blk - SB) * 4 + (t >> 6);
        if (r >= NREL) return;
        float x0 = inputr[r * F_OUT + lane];
        float x1 = inputr[r * F_OUT + 64 + lane];
        float p[N_HEAD];
        #pragma unroll
        for (int i = 0; i < N_HEAD; ++i)
            p[i] = x0 * a[(i * 2 + 1) * F_OUT + lane]
                 + x1 * a[(i * 2 + 1) * F_OUT + 64 + lane];
        #pragma unroll
        for (int off = 32; off > 0; off >>= 1) {
            #pragma unroll
            for (int i = 0; i < N_HEAD; ++i) p[i] += __shfl_down(p[i], off);
        }
        if (lane == 0)
            *(float4*)(reldot + r * 4) = make_float4(p[0], p[1], p[2], p[3]);
    } else {
        // ---- histogram of dst, 4 edges/thread, coalesced
        int hb = blk - SB - RB;
        #pragma unroll
        for (int k = 0; k < 4; ++k) {
            int e = (hb * 4 + k) * 256 + t;
            if (e < E) atomicAdd(&counts[A[e]], 1);
        }
    }
}

// ---- per-chunk sums (chunk = 2048 counts)
__global__ __launch_bounds__(256)
void block_sum_kernel(const int* __restrict__ counts, int* __restrict__ bsum, int N) {
    int blk = blockIdx.x, t = threadIdx.x;
    int base = blk * SCAN_CHUNK;
    int s = 0;
    #pragma unroll
    for (int k = 0; k < 8; ++k) {
        int idx = base + t + k * 256;
        if (idx < N) s += counts[idx];
    }
    #pragma unroll
    for (int off = 32; off > 0; off >>= 1) s += __shfl_down(s, off);
    __shared__ int red[4];
    if ((t & 63) == 0) red[t >> 6] = s;
    __syncthreads();
    if (t == 0) bsum[blk] = red[0] + red[1] + red[2] + red[3];
}

// ---- per-chunk exclusive scan + write offsets AND cursor (cursor = copy).
//      Each block redundantly wave-scans the <=64 partials (cheap, no extra
//      kernel, no extra global sync).
__global__ __launch_bounds__(256)
void scan_write_kernel(const int* __restrict__ counts, const int* __restrict__ bsum,
                       int* __restrict__ offsets, int* __restrict__ cursor,
                       int N, int NB, int E) {
    __shared__ int tsum[256];
    __shared__ int bbase_sh;
    int blk = blockIdx.x, t = threadIdx.x;
    if (t < 64) {
        int own = (t < NB) ? bsum[t] : 0;
        int v = own;
        #pragma unroll
        for (int off = 1; off < 64; off <<= 1) {
            int u = __shfl_up(v, off);
            if (t >= off) v += u;
        }
        if (t == blk) bbase_sh = v - own;   // exclusive prefix for this chunk
    }
    int base = blk * SCAN_CHUNK + t * 8;
    int v[8];
    #pragma unroll
    for (int k = 0; k < 8; ++k) {
        int idx = base + k;
        v[k] = (idx < N) ? counts[idx] : 0;
    }
    int s = 0;
    #pragma unroll
    for (int k = 0; k < 8; ++k) { int t0 = v[k]; v[k] = s; s += t0; }
    tsum[t] = s;
    __syncthreads();
    for (int off = 1; off < 256; off <<= 1) {
        int u = (t >= off) ? tsum[t - off] : 0;
        __syncthreads();
        tsum[t] += u;
        __syncthreads();
    }
    int tbase = bbase_sh + ((t == 0) ? 0 : tsum[t - 1]);
    #pragma unroll
    for (int k = 0; k < 8; ++k) {
        int idx = base + k;
        if (idx < N) {
            int o = tbase + v[k];
            offsets[idx] = o;
            cursor[idx] = o;
        }
    }
    if (blk == 0 && t == 0) offsets[N] = E;
}

// ---- scatter: one atomic bump on cursor, one scattered 4B write per edge.
__global__ __launch_bounds__(256)
void scatter_kernel(const int* __restrict__ A, int* __restrict__ cursor,
                    unsigned* __restrict__ sPK, int E) {
    #pragma unroll
    for (int k = 0; k < 4; ++k) {
        int e = (blockIdx.x * 4 + k) * 256 + threadIdx.x;
        if (e < E) {
            int dst = A[e];
            int rel = A[E + e];
            int src = A[2 * E + e];
            int idx = atomicAdd(&cursor[dst], 1);
            sPK[idx] = ((unsigned)rel << 16) | (unsigned)src;
        }
    }
}

// ============================================================================
// Per-node accumulation. grid=N, block=128 (thread = column). ee computed on
// the fly from srcdot/reldot during LDS staging (logit has no dst dependence).
// ============================================================================
#define STAGE 128
__global__ void __launch_bounds__(128)
node_kernel(const float* __restrict__ h, const float* __restrict__ inputr,
            const float* __restrict__ w,
            const float* __restrict__ srcdot, const float* __restrict__ reldot,
            const int* __restrict__ offsets, const unsigned* __restrict__ sPK,
            float* __restrict__ out, int N) {
    __shared__ float4 see[STAGE];
    __shared__ unsigned spk[STAGE];
    int n = blockIdx.x;
    int c = threadIdx.x;
    int s0 = offsets[n];
    int s1 = offsets[n + 1];
    float a1[N_HEAD] = {0, 0, 0, 0};
    float a2[N_HEAD] = {0, 0, 0, 0};
    float rs[N_HEAD] = {0, 0, 0, 0};
    for (int base = s0; base < s1; base += STAGE) {
        int cnt = min(STAGE, s1 - base);
        if (c < cnt) {
            unsigned pk = sPK[base + c];
            spk[c] = pk;
            float4 sd = *(const float4*)(srcdot + (pk & 0xFFFFu) * 4);
            float4 rd = *(const float4*)(reldot + (pk >> 16) * 4);
            float4 ee;
            float l;
            l = sd.x + rd.x; ee.x = __expf(-(l > 0.0f ? l : 0.2f * l));
            l = sd.y + rd.y; ee.y = __expf(-(l > 0.0f ? l : 0.2f * l));
            l = sd.z + rd.z; ee.z = __expf(-(l > 0.0f ? l : 0.2f * l));
            l = sd.w + rd.w; ee.w = __expf(-(l > 0.0f ? l : 0.2f * l));
            see[c] = ee;
        }
        __syncthreads();
        #pragma unroll 4
        for (int j = 0; j < cnt; ++j) {
            float4 ee = see[j];
            unsigned pk = spk[j];
            float hc = h[(pk & 0xFFFFu) * F_OUT + c];
            float rc = inputr[(pk >> 16) * F_OUT + c];
            a1[0] += hc * ee.x;  a2[0] += rc * ee.x;  rs[0] += ee.x;
            a1[1] += hc * ee.y;  a2[1] += rc * ee.y;  rs[1] += ee.y;
            a1[2] += hc * ee.z;  a2[2] += rc * ee.z;  rs[2] += ee.z;
            a1[3] += hc * ee.w;  a2[3] += rc * ee.w;  rs[3] += ee.w;
        }
        __syncthreads();
    }
    float cw1 = w[c];
    float cw2 = cw1 * w[F_OUT + c];
    float cw3 = cw2 * w[2 * F_OUT + c];
    float cwv[N_HEAD] = {1.0f, cw1, cw2, cw3};
    #pragma unroll
    for (int i = 0; i < N_HEAD; ++i) {
        out[((size_t)i * N + n) * F_OUT + c] = (cwv[i] * a1[i] - a2[i]) / rs[i];
    }
}

extern "C" void kernel_launch(void* const* d_in, const int* in_sizes, int n_in,
                              void* d_out, int out_size, void* d_ws, size_t ws_size,
                              hipStream_t stream) {
    const float* h      = (const float*)d_in[0];
    const float* inputr = (const float*)d_in[1];
    const float* w      = (const float*)d_in[2];
    const float* a      = (const float*)d_in[3];
    const int*   A      = (const int*)d_in[4];
    float* out = (float*)d_out;

    int N    = in_sizes[0] / F_OUT;   // 50000
    int NREL = in_sizes[1] / F_OUT;   // 500
    int E    = in_sizes[4] / 3;       // 600000
    int NB   = (N + SCAN_CHUNK - 1) / SCAN_CHUNK;   // 25
    int SB   = (N + 3) / 4;                          // srcdot blocks
    int RB   = (NREL + 3) / 4;                       // reldot blocks
    int HB   = (E + 1023) / 1024;                    // hist blocks

    char* ws = (char*)d_ws;
    float*    srcdot  = (float*)(ws + WS_SRCDOT);
    float*    reldot  = (float*)(ws + WS_RELDOT);
    int*      counts  = (int*)(ws + WS_COUNTS);
    int*      offsets = (int*)(ws + WS_OFFSETS);
    int*      cursor  = (int*)(ws + WS_CURSOR);
    int*      bsum    = (int*)(ws + WS_BSUM);
    unsigned* sPK     = (unsigned*)(ws + WS_SPK);

    hipMemsetAsync(counts, 0, (size_t)N * sizeof(int), stream);

    fused_pre<<<SB + RB + HB, 256, 0, stream>>>(h, inputr, w, a, A, srcdot, reldot,
                                                counts, N, NREL, E, SB, RB);
    block_sum_kernel<<<NB, 256, 0, stream>>>(counts, bsum, N);
    scan_write_kernel<<<NB, 256, 0, stream>>>(counts, bsum, offsets, cursor, N, NB, E);
    scatter_kernel<<<(E + 1023) / 1024, 256, 0, stream>>>(A, cursor, sPK, E);
    node_kernel<<<N, 128, 0, stream>>>(h, inputr, w, srcdot, reldot,
                                       offsets, sPK, out, N);
}